// Round 4
// baseline (271.629 us; speedup 1.0000x reference)
//
#include <hip/hip_runtime.h>

// ---------------------------------------------------------------------------
// Strategy: bucketed counting-sort + LDS segmented reduction.
//   Buckets of 128 consecutive fragment ids (nb = ceil(n_frag/128) <= 2048).
//   K1 hist:    per-block LDS histogram of fid>>7 -> global cnt[nb]
//   K2 scan:    single-block (1024 thr, chunked w/ carry) -> start, cursor
//   K3 scatter: per block: LDS hist of its chunk, one global atomicAdd per
//               (block,bucket) to reserve a range, LDS rank per atom,
//               write 32B payload (f, r, fid) to its slot.
//   K4 reduce:  one block per bucket: LDS acc[128][13] via ds_add_f32
//               (unsafeAtomicAdd - fire-and-forget, no CAS loop), then
//               per-fragment 3x3 double Cramer solve -> out.
// Fallback (ws too small / too many buckets): device-scope atomics (round-1).
// ---------------------------------------------------------------------------

#define BSHIFT 7
#define BFRAGS (1 << BSHIFT)   // 128 fragments per bucket
#define NBMAX  2048
#define NACC   13

// ---------------- fallback path (round-1, known correct) -------------------
__global__ void atom_accum_kernel(const float* __restrict__ f_atom,
                                  const float* __restrict__ atom_pos,
                                  const float* __restrict__ T_frag,
                                  const int*   __restrict__ frag_id,
                                  float* __restrict__ acc,
                                  int n_atom, int n_frag) {
    int i = blockIdx.x * blockDim.x + threadIdx.x;
    if (i >= n_atom) return;
    float fx = f_atom[3 * i + 0], fy = f_atom[3 * i + 1], fz = f_atom[3 * i + 2];
    float px = atom_pos[3 * i + 0], py = atom_pos[3 * i + 1], pz = atom_pos[3 * i + 2];
    int fid = frag_id[i];
    float rx = px - T_frag[3 * fid + 0];
    float ry = py - T_frag[3 * fid + 1];
    float rz = pz - T_frag[3 * fid + 2];
    atomicAdd(&acc[0 * n_frag + fid], 1.0f);
    atomicAdd(&acc[1 * n_frag + fid], fx);
    atomicAdd(&acc[2 * n_frag + fid], fy);
    atomicAdd(&acc[3 * n_frag + fid], fz);
    atomicAdd(&acc[4 * n_frag + fid], ry * fz - rz * fy);
    atomicAdd(&acc[5 * n_frag + fid], rz * fx - rx * fz);
    atomicAdd(&acc[6 * n_frag + fid], rx * fy - ry * fx);
    atomicAdd(&acc[7 * n_frag + fid], rx * rx);
    atomicAdd(&acc[8 * n_frag + fid], ry * ry);
    atomicAdd(&acc[9 * n_frag + fid], rz * rz);
    atomicAdd(&acc[10 * n_frag + fid], rx * ry);
    atomicAdd(&acc[11 * n_frag + fid], rx * rz);
    atomicAdd(&acc[12 * n_frag + fid], ry * rz);
}

// Shared finalize math (per fragment), in double for stability.
__device__ __forceinline__ void solve_frag(const float s[NACC], int fs,
                                           float* vout, float* oout) {
    float inv_cnt = 1.0f / fmaxf(s[0], 1.0f);
    vout[0] = s[1] * inv_cnt;
    vout[1] = s[2] * inv_cnt;
    vout[2] = s[3] * inv_cnt;

    double sxx = (double)s[7], syy = (double)s[8], szz = (double)s[9];
    double sxy = (double)s[10], sxz = (double)s[11], syz = (double)s[12];
    const double eps = 1e-4;
    double d = sxx + syy + szz;
    double a00 = d - sxx + eps, a11 = d - syy + eps, a22 = d - szz + eps;
    double a01 = -sxy, a02 = -sxz, a12 = -syz;

    double c00 = a11 * a22 - a12 * a12;
    double c01 = a02 * a12 - a01 * a22;
    double c02 = a01 * a12 - a02 * a11;
    double det = a00 * c00 + a01 * c01 + a02 * c02;
    double inv_det = (det != 0.0) ? 1.0 / det : 0.0;
    double c11 = a00 * a22 - a02 * a02;
    double c12 = a01 * a02 - a00 * a12;
    double c22 = a00 * a11 - a01 * a01;

    double tx = (double)s[4], ty = (double)s[5], tz = (double)s[6];
    if (fs <= 1) {
        oout[0] = 0.0f; oout[1] = 0.0f; oout[2] = 0.0f;
    } else {
        oout[0] = (float)((c00 * tx + c01 * ty + c02 * tz) * inv_det);
        oout[1] = (float)((c01 * tx + c11 * ty + c12 * tz) * inv_det);
        oout[2] = (float)((c02 * tx + c12 * ty + c22 * tz) * inv_det);
    }
}

__global__ void finalize_accum_kernel(const float* __restrict__ acc,
                                      const int* __restrict__ frag_sizes,
                                      float* __restrict__ out, int n_frag) {
    int i = blockIdx.x * blockDim.x + threadIdx.x;
    if (i >= n_frag) return;
    float s[NACC];
#pragma unroll
    for (int c = 0; c < NACC; ++c) s[c] = acc[(size_t)c * n_frag + i];
    float v[3], o[3];
    solve_frag(s, frag_sizes[i], v, o);
    out[3 * i + 0] = v[0]; out[3 * i + 1] = v[1]; out[3 * i + 2] = v[2];
    float* om = out + 3 * (size_t)n_frag;
    om[3 * i + 0] = o[0]; om[3 * i + 1] = o[1]; om[3 * i + 2] = o[2];
}

// ---------------- sort-based path ------------------------------------------

__global__ void hist_kernel(const int* __restrict__ frag_id,
                            unsigned* __restrict__ cnt, int n_atom, int nb) {
    __shared__ unsigned h[NBMAX];
    for (int t = threadIdx.x; t < NBMAX; t += blockDim.x) h[t] = 0;
    __syncthreads();
    int stride = gridDim.x * blockDim.x;
    for (int i = blockIdx.x * blockDim.x + threadIdx.x; i < n_atom; i += stride)
        atomicAdd(&h[frag_id[i] >> BSHIFT], 1u);
    __syncthreads();
    for (int t = threadIdx.x; t < nb; t += blockDim.x)
        if (h[t]) atomicAdd(&cnt[t], h[t]);
}

#define SCAN_T 1024
__global__ void scan_kernel(const unsigned* __restrict__ cnt,
                            unsigned* __restrict__ start,
                            unsigned* __restrict__ cursor, int nb) {
    __shared__ unsigned s[SCAN_T];
    __shared__ unsigned carry;
    int t = threadIdx.x;
    if (t == 0) carry = 0;
    __syncthreads();
    for (int base = 0; base < nb; base += SCAN_T) {
        int i = base + t;
        unsigned v = (i < nb) ? cnt[i] : 0u;
        s[t] = v;
        __syncthreads();
        for (int off = 1; off < SCAN_T; off <<= 1) {
            unsigned x = (t >= off) ? s[t - off] : 0u;
            __syncthreads();
            s[t] += x;
            __syncthreads();
        }
        unsigned c = carry;            // read old carry (all threads)
        if (i < nb) {
            unsigned st = c + s[t] - v;  // exclusive
            start[i] = st;
            cursor[i] = st;
        }
        __syncthreads();
        if (t == SCAN_T - 1) carry = c + s[t];
        __syncthreads();
    }
}

#define SC_CHUNK 16384
#define SC_THREADS 256

__global__ void scatter_kernel(const float* __restrict__ f_atom,
                               const float* __restrict__ atom_pos,
                               const float* __restrict__ T_frag,
                               const int* __restrict__ frag_id,
                               unsigned* __restrict__ cursor,
                               float* __restrict__ payload,
                               int n_atom, int nb) {
    __shared__ unsigned h[NBMAX];
    __shared__ unsigned base[NBMAX];
    int c0 = blockIdx.x * SC_CHUNK;

    for (int t = threadIdx.x; t < NBMAX; t += SC_THREADS) h[t] = 0;
    __syncthreads();
    for (int k = 0; k < SC_CHUNK; k += SC_THREADS) {
        int i = c0 + k + threadIdx.x;
        if (i < n_atom) atomicAdd(&h[frag_id[i] >> BSHIFT], 1u);
    }
    __syncthreads();
    for (int t = threadIdx.x; t < nb; t += SC_THREADS) {
        unsigned c = h[t];
        base[t] = c ? atomicAdd(&cursor[t], c) : 0u;
    }
    __syncthreads();
    for (int t = threadIdx.x; t < NBMAX; t += SC_THREADS) h[t] = 0;
    __syncthreads();

    for (int k = 0; k < SC_CHUNK; k += SC_THREADS) {
        int i = c0 + k + threadIdx.x;
        if (i >= n_atom) continue;
        int fid = frag_id[i];
        int b = fid >> BSHIFT;
        unsigned r = atomicAdd(&h[b], 1u);      // LDS rank (int: native ds_add_rtn)
        unsigned slot = base[b] + r;
        float fx = f_atom[3 * i + 0], fy = f_atom[3 * i + 1], fz = f_atom[3 * i + 2];
        float rx = atom_pos[3 * i + 0] - T_frag[3 * fid + 0];
        float ry = atom_pos[3 * i + 1] - T_frag[3 * fid + 1];
        float rz = atom_pos[3 * i + 2] - T_frag[3 * fid + 2];
        float4* p = (float4*)(payload + (size_t)slot * 8);
        p[0] = make_float4(fx, fy, fz, __int_as_float(fid));
        p[1] = make_float4(rx, ry, rz, 0.0f);
    }
}

__global__ void reduce_kernel(const float* __restrict__ payload,
                              const unsigned* __restrict__ cnt,
                              const unsigned* __restrict__ start,
                              const int* __restrict__ frag_sizes,
                              float* __restrict__ out, int n_frag) {
    __shared__ float acc[BFRAGS * NACC];   // 128*13*4 = 6656 B
    int b = blockIdx.x;
    for (int t = threadIdx.x; t < BFRAGS * NACC; t += blockDim.x) acc[t] = 0.0f;
    __syncthreads();

    unsigned n = cnt[b], s0 = start[b];
    for (unsigned t = threadIdx.x; t < n; t += blockDim.x) {
        const float4* p = (const float4*)(payload + (size_t)(s0 + t) * 8);
        float4 a = p[0];
        float4 c = p[1];
        float fx = a.x, fy = a.y, fz = a.z;
        int fid = __float_as_int(a.w);
        float rx = c.x, ry = c.y, rz = c.z;
        int lf = fid - (b << BSHIFT);
        float* A = &acc[lf * NACC];
        // unsafeAtomicAdd on LDS floats -> ds_add_f32 (fire-and-forget).
        // Plain atomicAdd would compile to a CAS loop (IEEE-safe lowering):
        // ~120cyc LDS round-trip x 13 x iters of serial latency (round-3 bug).
        unsafeAtomicAdd(&A[0], 1.0f);
        unsafeAtomicAdd(&A[1], fx);
        unsafeAtomicAdd(&A[2], fy);
        unsafeAtomicAdd(&A[3], fz);
        unsafeAtomicAdd(&A[4], ry * fz - rz * fy);
        unsafeAtomicAdd(&A[5], rz * fx - rx * fz);
        unsafeAtomicAdd(&A[6], rx * fy - ry * fx);
        unsafeAtomicAdd(&A[7], rx * rx);
        unsafeAtomicAdd(&A[8], ry * ry);
        unsafeAtomicAdd(&A[9], rz * rz);
        unsafeAtomicAdd(&A[10], rx * ry);
        unsafeAtomicAdd(&A[11], rx * rz);
        unsafeAtomicAdd(&A[12], ry * rz);
    }
    __syncthreads();

    int fid0 = b << BSHIFT;
    for (int lf = threadIdx.x; lf < BFRAGS; lf += blockDim.x) {
        int fid = fid0 + lf;
        if (fid >= n_frag) continue;
        float s[NACC];
#pragma unroll
        for (int c = 0; c < NACC; ++c) s[c] = acc[lf * NACC + c];
        float v[3], o[3];
        solve_frag(s, frag_sizes[fid], v, o);
        out[3 * fid + 0] = v[0]; out[3 * fid + 1] = v[1]; out[3 * fid + 2] = v[2];
        float* om = out + 3 * (size_t)n_frag;
        om[3 * fid + 0] = o[0]; om[3 * fid + 1] = o[1]; om[3 * fid + 2] = o[2];
    }
}

// ---------------------------------------------------------------------------

extern "C" void kernel_launch(void* const* d_in, const int* in_sizes, int n_in,
                              void* d_out, int out_size, void* d_ws, size_t ws_size,
                              hipStream_t stream) {
    const float* f_atom   = (const float*)d_in[0];
    const float* atom_pos = (const float*)d_in[1];
    const float* T_frag   = (const float*)d_in[2];
    const int*   frag_id  = (const int*)d_in[3];
    const int*   frag_sizes = (const int*)d_in[5];

    int n_atom = in_sizes[0] / 3;
    int n_frag = in_sizes[2] / 3;
    int nb = (n_frag + BFRAGS - 1) >> BSHIFT;

    // ws layout (sorted path): cnt[NBMAX] | start[NBMAX] | cursor[NBMAX] | payload
    size_t ctrl_bytes = (size_t)NBMAX * 3 * sizeof(unsigned);   // 24 KB
    size_t payload_bytes = (size_t)n_atom * 8 * sizeof(float);
    bool sorted_ok = (nb <= NBMAX) && (ws_size >= ctrl_bytes + payload_bytes);

    if (sorted_ok) {
        unsigned* cnt    = (unsigned*)d_ws;
        unsigned* start  = cnt + NBMAX;
        unsigned* cursor = start + NBMAX;
        float* payload   = (float*)((char*)d_ws + ctrl_bytes);

        hipMemsetAsync(cnt, 0, (size_t)nb * sizeof(unsigned), stream);

        hist_kernel<<<256, 256, 0, stream>>>(frag_id, cnt, n_atom, nb);
        scan_kernel<<<1, SCAN_T, 0, stream>>>(cnt, start, cursor, nb);
        int sc_blocks = (n_atom + SC_CHUNK - 1) / SC_CHUNK;
        scatter_kernel<<<sc_blocks, SC_THREADS, 0, stream>>>(
            f_atom, atom_pos, T_frag, frag_id, cursor, payload, n_atom, nb);
        reduce_kernel<<<nb, 256, 0, stream>>>(payload, cnt, start, frag_sizes,
                                              (float*)d_out, n_frag);
    } else {
        // fallback: direct device-scope atomic accumulation
        float* acc = (float*)d_ws;
        hipMemsetAsync(acc, 0, (size_t)NACC * n_frag * sizeof(float), stream);
        int threads = 256;
        atom_accum_kernel<<<(n_atom + threads - 1) / threads, threads, 0, stream>>>(
            f_atom, atom_pos, T_frag, frag_id, acc, n_atom, n_frag);
        finalize_accum_kernel<<<(n_frag + threads - 1) / threads, threads, 0, stream>>>(
            acc, frag_sizes, (float*)d_out, n_frag);
    }
}

// Round 5
// 205.716 us; speedup vs baseline: 1.3204x; 1.3204x over previous
//
#include <hip/hip_runtime.h>

// ---------------------------------------------------------------------------
// Zero-coordination bucketed sort + gather reduction.
//   Regions: scatter block k owns payload slots [k*SC_CHUNK, (k+1)*SC_CHUNK).
//   K1 scatter: per block: LDS hist of its 4096 atoms (buckets = fid>>7),
//               block-local exclusive scan, LDS-rank each atom, write 32B
//               payload (f, r, fid) bucket-grouped within own region, and
//               write offset row off[k][0..nb] (exclusive scan + total).
//               NO global atomics, NO cross-block coordination.
//   K2 reduce:  one block per bucket b: for each region k, read segment
//               [off[k][b], off[k][b+1]) of region k, accumulate 13 moments
//               in LDS via ds_add_f32 (unsafeAtomicAdd), then 3x3 double
//               Cramer solve per fragment -> out.
// Fallback (ws too small / too many buckets): device-scope atomics (round-1).
// ---------------------------------------------------------------------------

#define BSHIFT 7
#define BFRAGS (1 << BSHIFT)   // 128 fragments per bucket
#define NBMAX  2048
#define NACC   13

#define SC_CHUNK   4096
#define SC_THREADS 512
#define SEG 4                  // NBMAX / SC_THREADS

// ---------------- fallback path (round-1, known correct) -------------------
__global__ void atom_accum_kernel(const float* __restrict__ f_atom,
                                  const float* __restrict__ atom_pos,
                                  const float* __restrict__ T_frag,
                                  const int*   __restrict__ frag_id,
                                  float* __restrict__ acc,
                                  int n_atom, int n_frag) {
    int i = blockIdx.x * blockDim.x + threadIdx.x;
    if (i >= n_atom) return;
    float fx = f_atom[3 * i + 0], fy = f_atom[3 * i + 1], fz = f_atom[3 * i + 2];
    float px = atom_pos[3 * i + 0], py = atom_pos[3 * i + 1], pz = atom_pos[3 * i + 2];
    int fid = frag_id[i];
    float rx = px - T_frag[3 * fid + 0];
    float ry = py - T_frag[3 * fid + 1];
    float rz = pz - T_frag[3 * fid + 2];
    atomicAdd(&acc[0 * n_frag + fid], 1.0f);
    atomicAdd(&acc[1 * n_frag + fid], fx);
    atomicAdd(&acc[2 * n_frag + fid], fy);
    atomicAdd(&acc[3 * n_frag + fid], fz);
    atomicAdd(&acc[4 * n_frag + fid], ry * fz - rz * fy);
    atomicAdd(&acc[5 * n_frag + fid], rz * fx - rx * fz);
    atomicAdd(&acc[6 * n_frag + fid], rx * fy - ry * fx);
    atomicAdd(&acc[7 * n_frag + fid], rx * rx);
    atomicAdd(&acc[8 * n_frag + fid], ry * ry);
    atomicAdd(&acc[9 * n_frag + fid], rz * rz);
    atomicAdd(&acc[10 * n_frag + fid], rx * ry);
    atomicAdd(&acc[11 * n_frag + fid], rx * rz);
    atomicAdd(&acc[12 * n_frag + fid], ry * rz);
}

// Shared finalize math (per fragment), in double for stability.
__device__ __forceinline__ void solve_frag(const float s[NACC], int fs,
                                           float* vout, float* oout) {
    float inv_cnt = 1.0f / fmaxf(s[0], 1.0f);
    vout[0] = s[1] * inv_cnt;
    vout[1] = s[2] * inv_cnt;
    vout[2] = s[3] * inv_cnt;

    double sxx = (double)s[7], syy = (double)s[8], szz = (double)s[9];
    double sxy = (double)s[10], sxz = (double)s[11], syz = (double)s[12];
    const double eps = 1e-4;
    double d = sxx + syy + szz;
    double a00 = d - sxx + eps, a11 = d - syy + eps, a22 = d - szz + eps;
    double a01 = -sxy, a02 = -sxz, a12 = -syz;

    double c00 = a11 * a22 - a12 * a12;
    double c01 = a02 * a12 - a01 * a22;
    double c02 = a01 * a12 - a02 * a11;
    double det = a00 * c00 + a01 * c01 + a02 * c02;
    double inv_det = (det != 0.0) ? 1.0 / det : 0.0;
    double c11 = a00 * a22 - a02 * a02;
    double c12 = a01 * a02 - a00 * a12;
    double c22 = a00 * a11 - a01 * a01;

    double tx = (double)s[4], ty = (double)s[5], tz = (double)s[6];
    if (fs <= 1) {
        oout[0] = 0.0f; oout[1] = 0.0f; oout[2] = 0.0f;
    } else {
        oout[0] = (float)((c00 * tx + c01 * ty + c02 * tz) * inv_det);
        oout[1] = (float)((c01 * tx + c11 * ty + c12 * tz) * inv_det);
        oout[2] = (float)((c02 * tx + c12 * ty + c22 * tz) * inv_det);
    }
}

__global__ void finalize_accum_kernel(const float* __restrict__ acc,
                                      const int* __restrict__ frag_sizes,
                                      float* __restrict__ out, int n_frag) {
    int i = blockIdx.x * blockDim.x + threadIdx.x;
    if (i >= n_frag) return;
    float s[NACC];
#pragma unroll
    for (int c = 0; c < NACC; ++c) s[c] = acc[(size_t)c * n_frag + i];
    float v[3], o[3];
    solve_frag(s, frag_sizes[i], v, o);
    out[3 * i + 0] = v[0]; out[3 * i + 1] = v[1]; out[3 * i + 2] = v[2];
    float* om = out + 3 * (size_t)n_frag;
    om[3 * i + 0] = o[0]; om[3 * i + 1] = o[1]; om[3 * i + 2] = o[2];
}

// ---------------- zero-coordination sorted path ----------------------------

__global__ __launch_bounds__(SC_THREADS)
void scatter_kernel(const float* __restrict__ f_atom,
                    const float* __restrict__ atom_pos,
                    const float* __restrict__ T_frag,
                    const int* __restrict__ frag_id,
                    unsigned* __restrict__ off_g,   // [nreg][W], W = nb+1
                    float* __restrict__ payload,
                    int n_atom, int nb, int W) {
    __shared__ unsigned h[NBMAX];       // hist, then cursor
    __shared__ unsigned basex[NBMAX];   // exclusive starts (persist for off row)
    __shared__ unsigned s[SC_THREADS];
    __shared__ int fids[SC_CHUNK];

    int tid = threadIdx.x;
    int c0 = blockIdx.x * SC_CHUNK;

    for (int t = tid; t < NBMAX; t += SC_THREADS) h[t] = 0;
    __syncthreads();

    // pass 1: cache fids + LDS histogram
    for (int kk = 0; kk < SC_CHUNK; kk += SC_THREADS) {
        int i = c0 + kk + tid;
        if (i < n_atom) {
            int fid = frag_id[i];
            fids[kk + tid] = fid;
            atomicAdd(&h[fid >> BSHIFT], 1u);
        }
    }
    __syncthreads();

    // block-local exclusive scan of h[0..nb) -> basex; SEG entries per thread
    unsigned loc[SEG];
    unsigned psum = 0;
#pragma unroll
    for (int j = 0; j < SEG; ++j) {
        int i = tid * SEG + j;
        loc[j] = (i < nb) ? h[i] : 0u;
        psum += loc[j];
    }
    s[tid] = psum;
    __syncthreads();
    for (int o = 1; o < SC_THREADS; o <<= 1) {
        unsigned x = (tid >= o) ? s[tid - o] : 0u;
        __syncthreads();
        s[tid] += x;
        __syncthreads();
    }
    unsigned run = s[tid] - psum;   // exclusive base of this thread's segment
#pragma unroll
    for (int j = 0; j < SEG; ++j) {
        int i = tid * SEG + j;
        if (i < nb) basex[i] = run;
        run += loc[j];
    }
    __syncthreads();

    // write offset row (coalesced) and init cursors
    size_t rowbase = (size_t)blockIdx.x * W;
    for (int i = tid; i < nb; i += SC_THREADS) {
        off_g[rowbase + i] = basex[i];
        h[i] = basex[i];            // cursor
    }
    if (tid == SC_THREADS - 1) off_g[rowbase + nb] = s[tid];  // block total
    __syncthreads();

    // pass 2: rank via LDS cursor, compute payload, write into own region
    for (int kk = 0; kk < SC_CHUNK; kk += SC_THREADS) {
        int i = c0 + kk + tid;
        if (i >= n_atom) continue;
        int fid = fids[kk + tid];
        int b = fid >> BSHIFT;
        unsigned slot = atomicAdd(&h[b], 1u);   // ds_add_rtn_u32
        float fx = f_atom[3 * i + 0], fy = f_atom[3 * i + 1], fz = f_atom[3 * i + 2];
        float rx = atom_pos[3 * i + 0] - T_frag[3 * fid + 0];
        float ry = atom_pos[3 * i + 1] - T_frag[3 * fid + 1];
        float rz = atom_pos[3 * i + 2] - T_frag[3 * fid + 2];
        float4* p = (float4*)(payload + ((size_t)c0 + slot) * 8);
        p[0] = make_float4(fx, fy, fz, __int_as_float(fid));
        p[1] = make_float4(rx, ry, rz, 0.0f);
    }
}

__global__ void gather_reduce_kernel(const float* __restrict__ payload,
                                     const unsigned* __restrict__ off_g,
                                     const int* __restrict__ frag_sizes,
                                     float* __restrict__ out,
                                     int n_frag, int nb, int W, int nreg) {
    __shared__ float acc[BFRAGS * NACC];   // 128*13*4 = 6656 B
    int b = blockIdx.x;
    int tid = threadIdx.x;
    for (int t = tid; t < BFRAGS * NACC; t += blockDim.x) acc[t] = 0.0f;
    __syncthreads();

    for (int k = tid; k < nreg; k += blockDim.x) {
        size_t row = (size_t)k * W;
        unsigned o0 = off_g[row + b];
        unsigned o1 = off_g[row + b + 1];
        size_t base = (size_t)k * SC_CHUNK;
        for (unsigned j = o0; j < o1; ++j) {
            const float4* p = (const float4*)(payload + (base + j) * 8);
            float4 a = p[0];
            float4 c = p[1];
            float fx = a.x, fy = a.y, fz = a.z;
            int fid = __float_as_int(a.w);
            float rx = c.x, ry = c.y, rz = c.z;
            int lf = fid - (b << BSHIFT);
            float* A = &acc[lf * NACC];
            unsafeAtomicAdd(&A[0], 1.0f);
            unsafeAtomicAdd(&A[1], fx);
            unsafeAtomicAdd(&A[2], fy);
            unsafeAtomicAdd(&A[3], fz);
            unsafeAtomicAdd(&A[4], ry * fz - rz * fy);
            unsafeAtomicAdd(&A[5], rz * fx - rx * fz);
            unsafeAtomicAdd(&A[6], rx * fy - ry * fx);
            unsafeAtomicAdd(&A[7], rx * rx);
            unsafeAtomicAdd(&A[8], ry * ry);
            unsafeAtomicAdd(&A[9], rz * rz);
            unsafeAtomicAdd(&A[10], rx * ry);
            unsafeAtomicAdd(&A[11], rx * rz);
            unsafeAtomicAdd(&A[12], ry * rz);
        }
    }
    __syncthreads();

    int fid0 = b << BSHIFT;
    for (int lf = tid; lf < BFRAGS; lf += blockDim.x) {
        int fid = fid0 + lf;
        if (fid >= n_frag) continue;
        float sv[NACC];
#pragma unroll
        for (int c = 0; c < NACC; ++c) sv[c] = acc[lf * NACC + c];
        float v[3], o[3];
        solve_frag(sv, frag_sizes[fid], v, o);
        out[3 * fid + 0] = v[0]; out[3 * fid + 1] = v[1]; out[3 * fid + 2] = v[2];
        float* om = out + 3 * (size_t)n_frag;
        om[3 * fid + 0] = o[0]; om[3 * fid + 1] = o[1]; om[3 * fid + 2] = o[2];
    }
}

// ---------------------------------------------------------------------------

extern "C" void kernel_launch(void* const* d_in, const int* in_sizes, int n_in,
                              void* d_out, int out_size, void* d_ws, size_t ws_size,
                              hipStream_t stream) {
    const float* f_atom   = (const float*)d_in[0];
    const float* atom_pos = (const float*)d_in[1];
    const float* T_frag   = (const float*)d_in[2];
    const int*   frag_id  = (const int*)d_in[3];
    const int*   frag_sizes = (const int*)d_in[5];

    int n_atom = in_sizes[0] / 3;
    int n_frag = in_sizes[2] / 3;
    int nb = (n_frag + BFRAGS - 1) >> BSHIFT;
    int nreg = (n_atom + SC_CHUNK - 1) / SC_CHUNK;
    int W = nb + 1;

    // ws layout: off[nreg][W] (uint32) | pad to 256B | payload (n_atom slots * 32B)
    size_t off_bytes = ((size_t)nreg * W * sizeof(unsigned) + 255) & ~(size_t)255;
    size_t payload_bytes = (size_t)n_atom * 8 * sizeof(float);
    bool sorted_ok = (nb <= NBMAX) && (ws_size >= off_bytes + payload_bytes);

    if (sorted_ok) {
        unsigned* off_g = (unsigned*)d_ws;
        float* payload  = (float*)((char*)d_ws + off_bytes);

        scatter_kernel<<<nreg, SC_THREADS, 0, stream>>>(
            f_atom, atom_pos, T_frag, frag_id, off_g, payload, n_atom, nb, W);
        gather_reduce_kernel<<<nb, 256, 0, stream>>>(
            payload, off_g, frag_sizes, (float*)d_out, n_frag, nb, W, nreg);
    } else {
        // fallback: direct device-scope atomic accumulation
        float* acc = (float*)d_ws;
        hipMemsetAsync(acc, 0, (size_t)NACC * n_frag * sizeof(float), stream);
        int threads = 256;
        atom_accum_kernel<<<(n_atom + threads - 1) / threads, threads, 0, stream>>>(
            f_atom, atom_pos, T_frag, frag_id, acc, n_atom, n_frag);
        finalize_accum_kernel<<<(n_frag + threads - 1) / threads, threads, 0, stream>>>(
            acc, frag_sizes, (float*)d_out, n_frag);
    }
}